// Round 5
// baseline (114.120 us; speedup 1.0000x reference)
//
#include <hip/hip_runtime.h>

#define TT 4
#define BB 32
#define CC 256
#define NN 256
#define EPSf 1e-5f
#define MULTf 0.35355339059327373f
#define MARGINf 1e-3f
#define FLAG_CAP 524288u

typedef __attribute__((ext_vector_type(8))) short s16x8;
typedef __attribute__((ext_vector_type(4))) float f32x4;
typedef unsigned char uchar;
typedef unsigned int uint;
typedef unsigned short ushort;

// bf16 round-to-nearest-even
__device__ __forceinline__ ushort f2bf_rn(float f) {
  uint u = __float_as_uint(f);
  u = (u + 0x7FFFu + ((u >> 16) & 1u)) >> 16;
  return (ushort)u;
}
__device__ __forceinline__ float bf2f(ushort b) {
  return __uint_as_float(((uint)b) << 16);
}

__device__ __forceinline__ void gload_lds16(const void* g, void* l) {
  __builtin_amdgcn_global_load_lds(
      (const __attribute__((address_space(1))) uint*)g,
      (__attribute__((address_space(3))) uint*)l, 16, 0, 0);
}

// ---------------------------------------------------------------------------
// K1: xs = lif(x) fused with fragment layout (bf16 MFMA B-operand chunks)
//     + bit-packed spikes xsP (32 B per (t,b,n)).
// LIF bitwise-exact (halving exact, contract off).
// ---------------------------------------------------------------------------
__global__ __launch_bounds__(256) void k_lif_frag(const float* __restrict__ x,
                                                  uchar* __restrict__ xsF,
                                                  uchar* __restrict__ xsP) {
#pragma clang fp contract(off)
  const int tid = threadIdx.x;
  const int nt = blockIdx.x;   // n-tile
  const int ks = blockIdx.y;   // 0..7
  const int b = blockIdx.z;    // 0..31
  const int nl = tid & 63;
  const int oct = tid >> 6;    // 0..3
  const int n = nt * 64 + nl;
  const int c0 = ks * 32 + oct * 8;
  const size_t stride = (size_t)BB * CC * NN;
  const float* xb = x + ((size_t)b * CC + c0) * NN + n;

  float v[8];
#pragma unroll
  for (int j = 0; j < 8; ++j) v[j] = 0.f;

#pragma unroll
  for (int t = 0; t < TT; ++t) {
    ushort sp[8];
    uint pm = 0;
#pragma unroll
    for (int j = 0; j < 8; ++j) {
      float xt = xb[t * stride + (size_t)j * NN];
      float d = (xt - v[j]) * 0.5f;
      v[j] = v[j] + d;
      bool s = (v[j] >= 1.0f);
      sp[j] = s ? (ushort)0x3F80 : (ushort)0;
      if (s) { v[j] = 0.f; pm |= 1u << j; }
    }
    uint4* dst = reinterpret_cast<uint4*>(xsF) +
                 (((size_t)(t * BB + b) * 16 + (n >> 4)) * 512 + ks * 64 + oct * 16 + (n & 15));
    uint4 o;
    o.x = (uint)sp[0] | ((uint)sp[1] << 16);
    o.y = (uint)sp[2] | ((uint)sp[3] << 16);
    o.z = (uint)sp[4] | ((uint)sp[5] << 16);
    o.w = (uint)sp[6] | ((uint)sp[7] << 16);
    *dst = o;
    xsP[(((size_t)(t * BB + b) * NN + n) << 5) + ks * 4 + oct] = (uchar)pm;
  }
}

// ---------------------------------------------------------------------------
// K2: weight prep — 2-way bf16 split, MFMA-fragment-ready layout.
// Also zeroes the flag counter (replaces hipMemsetAsync kernel launch).
// ---------------------------------------------------------------------------
__global__ __launch_bounds__(256) void k_prep_w(
    const float* __restrict__ qw, const float* __restrict__ kw,
    const float* __restrict__ vw, const float* __restrict__ pw,
    uchar* __restrict__ wfq, uchar* __restrict__ wfp,
    uint* __restrict__ flags) {
  const int gid = blockIdx.x * 256 + threadIdx.x;  // 0..32767
  if (gid < 4) flags[gid] = 0;
  const int ob2 = gid >> 9;                        // 0..63
  const int e = gid & 511;
  const int ks = e >> 6, l = e & 63;
  const float* W;
  uchar* outb;
  int ob_out, nob;
  if (ob2 < 48) {
    const int sel = ob2 >> 4;
    W = sel == 0 ? qw : (sel == 1 ? kw : vw);
    W += ((size_t)((ob2 & 15) * 16 + (l & 15))) * CC;
    outb = wfq; ob_out = ob2; nob = 48;
  } else {
    W = pw + ((size_t)((ob2 - 48) * 16 + (l & 15))) * CC;
    outb = wfp; ob_out = ob2 - 48; nob = 16;
  }
  const int c0 = ks * 32 + (l >> 4) * 8;
  float wv[8];
  *reinterpret_cast<float4*>(&wv[0]) = *reinterpret_cast<const float4*>(W + c0);
  *reinterpret_cast<float4*>(&wv[4]) = *reinterpret_cast<const float4*>(W + c0 + 4);
  ushort hi[8], lo[8];
#pragma unroll
  for (int j = 0; j < 8; ++j) {
    hi[j] = f2bf_rn(wv[j]);
    lo[j] = f2bf_rn(wv[j] - bf2f(hi[j]));
  }
  const size_t base = (((size_t)ob_out * 8 + ks) * 64 + l) * 16;
  const size_t sstr = (size_t)nob * 8 * 64 * 16;
  *reinterpret_cast<uint4*>(outb + base) = *reinterpret_cast<const uint4*>(hi);
  *reinterpret_cast<uint4*>(outb + sstr + base) = *reinterpret_cast<const uint4*>(lo);
}

// ---------------------------------------------------------------------------
// K4: fused q/k/v conv (MFMA, 2-split bf16) + BN + LIF, double-buffered LDS.
// Prefetch t+1 overlaps compute of t; spike stores deferred to registers.
// ---------------------------------------------------------------------------
__global__ __launch_bounds__(256, 2) void k_qkv_mfma(
    const uchar* __restrict__ xsF, const uchar* __restrict__ wfq,
    const float* __restrict__ qga, const float* __restrict__ qbe, const float* __restrict__ qme, const float* __restrict__ qva,
    const float* __restrict__ kga, const float* __restrict__ kbe, const float* __restrict__ kme, const float* __restrict__ kva,
    const float* __restrict__ vga, const float* __restrict__ vbe, const float* __restrict__ vme, const float* __restrict__ vva,
    ushort* __restrict__ qp, uint* __restrict__ flags) {
  __shared__ short lsB[2][4][8][64][8];  // 2 x 32KB
  const int tid = threadIdx.x;
  const int w = tid >> 6, lane = tid & 63;
  const int lhi = lane >> 4, llo = lane & 15;
  const int wr = w >> 1, wc = w & 1;
  const int oc0 = blockIdx.x * 64;
  const int ntile = blockIdx.y;
  const int b = blockIdx.z;
  const int sel = oc0 >> 8;
  const float* G  = sel == 0 ? qga : (sel == 1 ? kga : vga);
  const float* Be = sel == 0 ? qbe : (sel == 1 ? kbe : vbe);
  const float* Mn = sel == 0 ? qme : (sel == 1 ? kme : vme);
  const float* Vr = sel == 0 ? qva : (sel == 1 ? kva : vva);

  s16x8 wfr[2][2][8];
#pragma unroll
  for (int s = 0; s < 2; ++s)
#pragma unroll
    for (int mf = 0; mf < 2; ++mf) {
      const int ob = blockIdx.x * 4 + wr * 2 + mf;
#pragma unroll
      for (int ks = 0; ks < 8; ++ks)
        wfr[s][mf][ks] = *reinterpret_cast<const s16x8*>(
            wfq + ((((size_t)s * 48 + ob) * 8 + ks) * 64 + lane) * 16);
    }

  float inv8[2][4], mean8[2][4], beta8[2][4];
#pragma unroll
  for (int mf = 0; mf < 2; ++mf)
#pragma unroll
    for (int r = 0; r < 4; ++r) {
      const int ocb = (oc0 & 255) + wr * 32 + mf * 16 + lhi * 4 + r;
      inv8[mf][r] = G[ocb] / sqrtf(Vr[ocb] + EPSf);
      mean8[mf][r] = Mn[ocb];
      beta8[mf][r] = Be[ocb];
    }

  auto STAGE = [&](int buf, int t) {
    const uchar* src = xsF + (((size_t)(t * BB + b) * 16 + ntile * 4) * 8192);
#pragma unroll
    for (int k2 = 0; k2 < 8; ++k2) {
      const int chunk = w * 8 + k2;
      gload_lds16(src + (size_t)chunk * 1024 + lane * 16,
                  reinterpret_cast<char*>(&lsB[buf][0][0][0][0]) + chunk * 1024);
    }
  };

  float vst[2][2][4];
#pragma unroll
  for (int mf = 0; mf < 2; ++mf)
#pragma unroll
    for (int nf = 0; nf < 2; ++nf)
#pragma unroll
      for (int r = 0; r < 4; ++r) vst[mf][nf][r] = 0.f;
  uint fl = 0;
  ushort qm[TT][4];  // [t][mf*2+nf], meaningful for lanes with llo<4 (r=llo)

  STAGE(0, 0);
  __syncthreads();

#pragma unroll
  for (int t = 0; t < TT; ++t) {
    const int cur = t & 1;
    if (t + 1 < TT) STAGE(cur ^ 1, t + 1);

    f32x4 acc[2][2];
#pragma unroll
    for (int mf = 0; mf < 2; ++mf)
#pragma unroll
      for (int nf = 0; nf < 2; ++nf) acc[mf][nf] = (f32x4){0.f, 0.f, 0.f, 0.f};

#pragma unroll
    for (int ks = 0; ks < 8; ++ks) {
      s16x8 b0 = *reinterpret_cast<const s16x8*>(&lsB[cur][wc * 2][ks][lane][0]);
      s16x8 b1 = *reinterpret_cast<const s16x8*>(&lsB[cur][wc * 2 + 1][ks][lane][0]);
#pragma unroll
      for (int s = 0; s < 2; ++s)
#pragma unroll
        for (int mf = 0; mf < 2; ++mf) {
          acc[mf][0] = __builtin_amdgcn_mfma_f32_16x16x32_bf16(wfr[s][mf][ks], b0, acc[mf][0], 0, 0, 0);
          acc[mf][1] = __builtin_amdgcn_mfma_f32_16x16x32_bf16(wfr[s][mf][ks], b1, acc[mf][1], 0, 0, 0);
        }
    }

    // BN + LIF epilogue (registers only; stores deferred)
#pragma unroll
    for (int mf = 0; mf < 2; ++mf)
#pragma unroll
      for (int nf = 0; nf < 2; ++nf)
#pragma unroll
        for (int r = 0; r < 4; ++r) {
          float y = (acc[mf][nf][r] - mean8[mf][r]) * inv8[mf][r] + beta8[mf][r];
          float v = vst[mf][nf][r];
          v = v + (y - v) * 0.5f;
          const bool sp = (v >= 1.0f);
          if (fabsf(v - 1.0f) < MARGINf) fl |= 1u << ((mf * 2 + nf) * 4 + r);
          const unsigned long long m = __ballot(sp);
          if (llo == r) qm[t][mf * 2 + nf] = (ushort)((m >> (lhi * 16)) & 0xFFFFull);
          vst[mf][nf][r] = sp ? 0.f : v;
        }
    __syncthreads();  // drains prefetch (landed under compute) + LDS reads
  }

  // deferred packed-spike writes
  if (llo < 4) {
#pragma unroll
    for (int t = 0; t < TT; ++t) {
      ushort* qrow = qp + (size_t)(t * BB + b) * 768 * 16;
#pragma unroll
      for (int mf = 0; mf < 2; ++mf)
#pragma unroll
        for (int nf = 0; nf < 2; ++nf) {
          const int oc = oc0 + wr * 32 + mf * 16 + lhi * 4 + llo;
          qrow[(size_t)oc * 16 + ntile * 4 + wc * 2 + nf] = qm[t][mf * 2 + nf];
        }
    }
  }

  if (fl) {
    const int cnt = __popc(fl);
    uint base = atomicAdd(flags, (uint)cnt);
#pragma unroll
    for (int mf = 0; mf < 2; ++mf)
#pragma unroll
      for (int nf = 0; nf < 2; ++nf)
#pragma unroll
        for (int r = 0; r < 4; ++r)
          if (fl & (1u << ((mf * 2 + nf) * 4 + r))) {
            const int oc = oc0 + wr * 32 + mf * 16 + lhi * 4 + r;
            const int n = ntile * 64 + wc * 32 + nf * 16 + llo;
            if (base < FLAG_CAP) flags[4 + base] = (((uint)(b << 10) | (uint)oc) << 8) | (uint)n;
            base++;
          }
  }
}

// ---------------------------------------------------------------------------
// K5: exact fixer on packed spike bits (validated round-3 version).
// ---------------------------------------------------------------------------
__global__ __launch_bounds__(256) void k_fix(
    const uchar* __restrict__ xsP,
    const float* __restrict__ qw, const float* __restrict__ kw, const float* __restrict__ vw,
    const float* __restrict__ qga, const float* __restrict__ qbe, const float* __restrict__ qme, const float* __restrict__ qva,
    const float* __restrict__ kga, const float* __restrict__ kbe, const float* __restrict__ kme, const float* __restrict__ kva,
    const float* __restrict__ vga, const float* __restrict__ vbe, const float* __restrict__ vme, const float* __restrict__ vva,
    uint* __restrict__ qp32, const uint* __restrict__ flags) {
#pragma clang fp contract(off)
  const uint cnt = min(flags[0], FLAG_CAP);
  for (uint i = blockIdx.x * 256 + threadIdx.x; i < cnt; i += gridDim.x * 256) {
    const uint e = flags[4 + i];
    const int n = e & 255;
    const int oc = (e >> 8) & 1023;
    const int b = e >> 18;
    const int sel = oc >> 8, ocl = oc & 255;
    const float* W = (sel == 0 ? qw : (sel == 1 ? kw : vw)) + (size_t)ocl * CC;
    const float* G  = sel == 0 ? qga : (sel == 1 ? kga : vga);
    const float* Be = sel == 0 ? qbe : (sel == 1 ? kbe : vbe);
    const float* Mn = sel == 0 ? qme : (sel == 1 ? kme : vme);
    const float* Vr = sel == 0 ? qva : (sel == 1 ? kva : vva);

    uint bw[4][8];
#pragma unroll
    for (int t = 0; t < TT; ++t) {
      const uint4* p = reinterpret_cast<const uint4*>(
          xsP + (((size_t)(t * BB + b) * NN + n) << 5));
      uint4 a = p[0], c4 = p[1];
      bw[t][0] = a.x;  bw[t][1] = a.y;  bw[t][2] = a.z;  bw[t][3] = a.w;
      bw[t][4] = c4.x; bw[t][5] = c4.y; bw[t][6] = c4.z; bw[t][7] = c4.w;
    }

    const float4* W4 = reinterpret_cast<const float4*>(W);
    float a0 = 0.f, a1 = 0.f, a2 = 0.f, a3 = 0.f;
#pragma unroll
    for (int g = 0; g < 32; ++g) {
      const float4 w0 = W4[2 * g];
      const float4 w1 = W4[2 * g + 1];
      const uint s0 = bw[0][g >> 2] >> ((g & 3) * 8);
      const uint s1 = bw[1][g >> 2] >> ((g & 3) * 8);
      const uint s2 = bw[2][g >> 2] >> ((g & 3) * 8);
      const uint s3 = bw[3][g >> 2] >> ((g & 3) * 8);
      const float wv[8] = {w0.x, w0.y, w0.z, w0.w, w1.x, w1.y, w1.z, w1.w};
#pragma unroll
      for (int j = 0; j < 8; ++j) {
        a0 = fmaf(wv[j], (float)((s0 >> j) & 1u), a0);
        a1 = fmaf(wv[j], (float)((s1 >> j) & 1u), a1);
        a2 = fmaf(wv[j], (float)((s2 >> j) & 1u), a2);
        a3 = fmaf(wv[j], (float)((s3 >> j) & 1u), a3);
      }
    }
    float accs[4] = {a0, a1, a2, a3};

    const float inv = G[ocl] / sqrtf(Vr[ocl] + EPSf);
    const float mean = Mn[ocl], beta = Be[ocl];
    float v = 0.f;
#pragma unroll
    for (int t = 0; t < TT; ++t) {
      float xm = accs[t] - mean;
      float y = xm * inv;
      y = y + beta;
      float d = (y - v) * 0.5f;
      v = v + d;
      const bool sp = (v >= 1.0f);
      const size_t widx = ((size_t)(t * BB + b) * 768 + oc) * 8 + (n >> 5);
      const uint bit = 1u << (n & 31);
      if (sp) atomicOr(&qp32[widx], bit);
      else atomicAnd(&qp32[widx], ~bit);
      if (sp) v = 0.f;
    }
  }
}

// ---------------------------------------------------------------------------
// K6: attention Q(K^T V)*2scale + LIF, exact integers, 1024-thread blocks.
// thread = (n, jg): 8 output channels per thread; KtV one entry per thread;
// wave-uniform jg keeps all KtV reads broadcast (conflict-free).
// ---------------------------------------------------------------------------
__global__ __launch_bounds__(1024) void k_attn(const ushort* __restrict__ qp,
                                               uchar* __restrict__ attnF) {
  __shared__ uint Qb[32][8], Kb[32][8], Vb[32][8];
  __shared__ int KtV[32][32];
  const int tid = threadIdx.x;
  const int b = blockIdx.x >> 3;
  const int h = blockIdx.x & 7;
  const int n = tid & 255;
  const int jg = tid >> 8;  // 0..3, wave-uniform
  const int wordn = n >> 5, bitn = n & 31;

  float vst[8];
#pragma unroll
  for (int j = 0; j < 8; ++j) vst[j] = 0.f;

  for (int t = 0; t < TT; ++t) {
    __syncthreads();
    const ushort* base = qp + (size_t)(t * BB + b) * 768 * 16;
    if (tid < 768) {
      const int arr = tid >> 8;  // 0=Q 1=K 2=V
      const int idx = tid & 255;
      const int ch = idx >> 3, wv2 = idx & 7;
      const uint val = *reinterpret_cast<const uint*>(
          base + (size_t)(arr * 256 + h * 32 + ch) * 16 + wv2 * 2);
      uint(*dst)[8] = (arr == 0) ? Qb : (arr == 1) ? Kb : Vb;
      dst[ch][wv2] = val;
    }
    __syncthreads();
    {
      const int ii = tid >> 5, jj = tid & 31;
      int s = 0;
#pragma unroll
      for (int w8 = 0; w8 < 8; ++w8) s += __popc(Kb[ii][w8] & Vb[jj][w8]);
      KtV[ii][jj] = s;
    }
    __syncthreads();
    int acc[8];
#pragma unroll
    for (int j = 0; j < 8; ++j) acc[j] = 0;
#pragma unroll 4
    for (int ii = 0; ii < 32; ++ii) {
      const int qb = (int)((Qb[ii][wordn] >> bitn) & 1u);
      const int4 k0 = *reinterpret_cast<const int4*>(&KtV[ii][jg * 8]);
      const int4 k1 = *reinterpret_cast<const int4*>(&KtV[ii][jg * 8 + 4]);
      acc[0] += k0.x * qb; acc[1] += k0.y * qb;
      acc[2] += k0.z * qb; acc[3] += k0.w * qb;
      acc[4] += k1.x * qb; acc[5] += k1.y * qb;
      acc[6] += k1.z * qb; acc[7] += k1.w * qb;
    }
    // scale + LIF -> bf16 spike chunk write
    ushort sbit[8];
    {
#pragma clang fp contract(off)
#pragma unroll
      for (int j = 0; j < 8; ++j) {
        float y = (float)acc[j] * MULTf;
        float v = vst[j];
        float d = (y - v) * 0.5f;
        v = v + d;
        const bool sp = (v >= 1.0f);
        sbit[j] = sp ? (ushort)0x3F80 : (ushort)0;
        vst[j] = sp ? 0.f : v;
      }
    }
    uint4 o;
    o.x = (uint)sbit[0] | ((uint)sbit[1] << 16);
    o.y = (uint)sbit[2] | ((uint)sbit[3] << 16);
    o.z = (uint)sbit[4] | ((uint)sbit[5] << 16);
    o.w = (uint)sbit[6] | ((uint)sbit[7] << 16);
    uint4* dst4 = reinterpret_cast<uint4*>(attnF) +
                  (((size_t)(t * BB + b) * 16 + (n >> 4)) * 512 + h * 64 + jg * 16 + (n & 15));
    *dst4 = o;
  }
}

// ---------------------------------------------------------------------------
// K7: proj conv (MFMA, 2-split) + BN -> f32 out.
// ---------------------------------------------------------------------------
__global__ __launch_bounds__(256, 2) void k_proj_mfma(
    const uchar* __restrict__ attnF, const uchar* __restrict__ wfp,
    const float* __restrict__ pga, const float* __restrict__ pbe,
    const float* __restrict__ pme, const float* __restrict__ pva,
    float* __restrict__ out) {
  __shared__ short lsB[4][8][64][8];
  const int tid = threadIdx.x;
  const int w = tid >> 6, lane = tid & 63;
  const int lhi = lane >> 4, llo = lane & 15;
  const int wr = w >> 1, wc = w & 1;
  const int oc0 = blockIdx.x * 64;
  const int ntile = blockIdx.y;
  const int tb = blockIdx.z;

  s16x8 wfr[2][2][8];
#pragma unroll
  for (int s = 0; s < 2; ++s)
#pragma unroll
    for (int mf = 0; mf < 2; ++mf) {
      const int ob = blockIdx.x * 4 + wr * 2 + mf;
#pragma unroll
      for (int ks = 0; ks < 8; ++ks)
        wfr[s][mf][ks] = *reinterpret_cast<const s16x8*>(
            wfp + ((((size_t)s * 16 + ob) * 8 + ks) * 64 + lane) * 16);
    }

  float inv8[2][4], mean8[2][4], beta8[2][4];
#pragma unroll
  for (int mf = 0; mf < 2; ++mf)
#pragma unroll
    for (int r = 0; r < 4; ++r) {
      const int ocb = oc0 + wr * 32 + mf * 16 + lhi * 4 + r;
      inv8[mf][r] = pga[ocb] / sqrtf(pva[ocb] + EPSf);
      mean8[mf][r] = pme[ocb];
      beta8[mf][r] = pbe[ocb];
    }

  const uchar* src = attnF + (((size_t)tb * 16 + ntile * 4) * 8192);
#pragma unroll
  for (int k2 = 0; k2 < 8; ++k2) {
    const int chunk = w * 8 + k2;
    gload_lds16(src + (size_t)chunk * 1024 + lane * 16,
                reinterpret_cast<char*>(&lsB[0][0][0][0]) + chunk * 1024);
  }
  __syncthreads();

  f32x4 acc[2][2];
#pragma unroll
  for (int mf = 0; mf < 2; ++mf)
#pragma unroll
    for (int nf = 0; nf < 2; ++nf) acc[mf][nf] = (f32x4){0.f, 0.f, 0.f, 0.f};

#pragma unroll
  for (int ks = 0; ks < 8; ++ks) {
    s16x8 b0 = *reinterpret_cast<const s16x8*>(&lsB[wc * 2][ks][lane][0]);
    s16x8 b1 = *reinterpret_cast<const s16x8*>(&lsB[wc * 2 + 1][ks][lane][0]);
#pragma unroll
    for (int s = 0; s < 2; ++s)
#pragma unroll
      for (int mf = 0; mf < 2; ++mf) {
        acc[mf][0] = __builtin_amdgcn_mfma_f32_16x16x32_bf16(wfr[s][mf][ks], b0, acc[mf][0], 0, 0, 0);
        acc[mf][1] = __builtin_amdgcn_mfma_f32_16x16x32_bf16(wfr[s][mf][ks], b1, acc[mf][1], 0, 0, 0);
      }
  }

#pragma unroll
  for (int mf = 0; mf < 2; ++mf)
#pragma unroll
    for (int nf = 0; nf < 2; ++nf)
#pragma unroll
      for (int r = 0; r < 4; ++r) {
        const int oc = oc0 + wr * 32 + mf * 16 + lhi * 4 + r;
        const int nn = ntile * 64 + wc * 32 + nf * 16 + llo;
        float y = (acc[mf][nf][r] - mean8[mf][r]) * inv8[mf][r] + beta8[mf][r];
        out[((size_t)tb * CC + oc) * NN + nn] = y;
      }
}

// ---------------------------------------------------------------------------
extern "C" void kernel_launch(void* const* d_in, const int* in_sizes, int n_in,
                              void* d_out, int out_size, void* d_ws, size_t ws_size,
                              hipStream_t stream) {
  const float* x = (const float*)d_in[0];
  const float* q_w = (const float*)d_in[1];
  const float* q_g = (const float*)d_in[2];
  const float* q_b = (const float*)d_in[3];
  const float* q_m = (const float*)d_in[4];
  const float* q_v = (const float*)d_in[5];
  const float* k_w = (const float*)d_in[6];
  const float* k_g = (const float*)d_in[7];
  const float* k_b = (const float*)d_in[8];
  const float* k_m = (const float*)d_in[9];
  const float* k_v = (const float*)d_in[10];
  const float* v_w = (const float*)d_in[11];
  const float* v_g = (const float*)d_in[12];
  const float* v_b = (const float*)d_in[13];
  const float* v_m = (const float*)d_in[14];
  const float* v_v = (const float*)d_in[15];
  const float* p_w = (const float*)d_in[16];
  const float* p_g = (const float*)d_in[17];
  const float* p_b = (const float*)d_in[18];
  const float* p_m = (const float*)d_in[19];
  const float* p_v = (const float*)d_in[20];

  uchar* ws = (uchar*)d_ws;
  uchar* xsF  = ws;                         // 16 MiB frags (reused as attnF)
  ushort* qp  = (ushort*)(ws + 16777216);   // 3 MiB packed q/k/v spikes
  uchar* wfq  = ws + 19922944;              // 768 KiB
  uchar* wfp  = ws + 20709376;              // 256 KiB
  uint* flags = (uint*)(ws + 20971520);     // 16 B counter + list (2 MiB)
  uchar* xsP  = ws + 23068672;              // 1 MiB bit-packed xs spikes

  k_prep_w<<<dim3(128), 256, 0, stream>>>(q_w, k_w, v_w, p_w, wfq, wfp, flags);
  k_lif_frag<<<dim3(4, 8, 32), 256, 0, stream>>>(x, xsF, xsP);
  k_qkv_mfma<<<dim3(12, 4, 32), 256, 0, stream>>>(xsF, wfq,
                                                  q_g, q_b, q_m, q_v,
                                                  k_g, k_b, k_m, k_v,
                                                  v_g, v_b, v_m, v_v,
                                                  qp, flags);
  k_fix<<<dim3(64), 256, 0, stream>>>(xsP, q_w, k_w, v_w,
                                      q_g, q_b, q_m, q_v,
                                      k_g, k_b, k_m, k_v,
                                      v_g, v_b, v_m, v_v,
                                      (uint*)qp, flags);
  k_attn<<<dim3(256), 1024, 0, stream>>>(qp, xsF /* attnF shares region */);
  k_proj_mfma<<<dim3(4, 4, 128), 256, 0, stream>>>(xsF, wfp, p_g, p_b, p_m, p_v,
                                                   (float*)d_out);
}

// Round 6
// 112.339 us; speedup vs baseline: 1.0159x; 1.0159x over previous
//
#include <hip/hip_runtime.h>

#define TT 4
#define BB 32
#define CC 256
#define NN 256
#define EPSf 1e-5f
#define MULTf 0.35355339059327373f
#define MARGINf 1e-3f
#define FLAG_CAP 524288u

typedef __attribute__((ext_vector_type(8))) short s16x8;
typedef __attribute__((ext_vector_type(4))) float f32x4;
typedef unsigned char uchar;
typedef unsigned int uint;
typedef unsigned short ushort;

// bf16 round-to-nearest-even
__device__ __forceinline__ ushort f2bf_rn(float f) {
  uint u = __float_as_uint(f);
  u = (u + 0x7FFFu + ((u >> 16) & 1u)) >> 16;
  return (ushort)u;
}
__device__ __forceinline__ float bf2f(ushort b) {
  return __uint_as_float(((uint)b) << 16);
}

__device__ __forceinline__ void gload_lds16(const void* g, void* l) {
  __builtin_amdgcn_global_load_lds(
      (const __attribute__((address_space(1))) uint*)g,
      (__attribute__((address_space(3))) uint*)l, 16, 0, 0);
}

// ---------------------------------------------------------------------------
// K1 (merged): blocks 0..1023 = lif(x) -> xsF fragments + xsP packed bits;
//              blocks 1024..1151 = weight prep (2-way bf16 split) + flag zero.
// LIF bitwise-exact (halving exact, contract off).
// ---------------------------------------------------------------------------
__global__ __launch_bounds__(256) void k_front(
    const float* __restrict__ x, uchar* __restrict__ xsF, uchar* __restrict__ xsP,
    const float* __restrict__ qw, const float* __restrict__ kw,
    const float* __restrict__ vw, const float* __restrict__ pw,
    uchar* __restrict__ wfq, uchar* __restrict__ wfp, uint* __restrict__ flags) {
  const int tid = threadIdx.x;
  const int bid = blockIdx.x;
  if (bid < 1024) {
#pragma clang fp contract(off)
    const int nt = bid & 3;          // n-tile
    const int ks = (bid >> 2) & 7;   // 0..7
    const int b = bid >> 5;          // 0..31
    const int nl = tid & 63;
    const int oct = tid >> 6;        // 0..3
    const int n = nt * 64 + nl;
    const int c0 = ks * 32 + oct * 8;
    const size_t stride = (size_t)BB * CC * NN;
    const float* xb = x + ((size_t)b * CC + c0) * NN + n;

    float v[8];
#pragma unroll
    for (int j = 0; j < 8; ++j) v[j] = 0.f;

#pragma unroll
    for (int t = 0; t < TT; ++t) {
      ushort sp[8];
      uint pm = 0;
#pragma unroll
      for (int j = 0; j < 8; ++j) {
        float xt = xb[t * stride + (size_t)j * NN];
        float d = (xt - v[j]) * 0.5f;
        v[j] = v[j] + d;
        bool s = (v[j] >= 1.0f);
        sp[j] = s ? (ushort)0x3F80 : (ushort)0;
        if (s) { v[j] = 0.f; pm |= 1u << j; }
      }
      uint4* dst = reinterpret_cast<uint4*>(xsF) +
                   (((size_t)(t * BB + b) * 16 + (n >> 4)) * 512 + ks * 64 + oct * 16 + (n & 15));
      uint4 o;
      o.x = (uint)sp[0] | ((uint)sp[1] << 16);
      o.y = (uint)sp[2] | ((uint)sp[3] << 16);
      o.z = (uint)sp[4] | ((uint)sp[5] << 16);
      o.w = (uint)sp[6] | ((uint)sp[7] << 16);
      *dst = o;
      xsP[(((size_t)(t * BB + b) * NN + n) << 5) + ks * 4 + oct] = (uchar)pm;
    }
  } else {
    const int gid = (bid - 1024) * 256 + tid;  // 0..32767
    if (gid < 4) flags[gid] = 0;
    const int ob2 = gid >> 9;                  // 0..63
    const int e = gid & 511;
    const int ks = e >> 6, l = e & 63;
    const float* W;
    uchar* outb;
    int ob_out, nob;
    if (ob2 < 48) {
      const int sel = ob2 >> 4;
      W = sel == 0 ? qw : (sel == 1 ? kw : vw);
      W += ((size_t)((ob2 & 15) * 16 + (l & 15))) * CC;
      outb = wfq; ob_out = ob2; nob = 48;
    } else {
      W = pw + ((size_t)((ob2 - 48) * 16 + (l & 15))) * CC;
      outb = wfp; ob_out = ob2 - 48; nob = 16;
    }
    const int c0 = ks * 32 + (l >> 4) * 8;
    float wv[8];
    *reinterpret_cast<float4*>(&wv[0]) = *reinterpret_cast<const float4*>(W + c0);
    *reinterpret_cast<float4*>(&wv[4]) = *reinterpret_cast<const float4*>(W + c0 + 4);
    ushort hi[8], lo[8];
#pragma unroll
    for (int j = 0; j < 8; ++j) {
      hi[j] = f2bf_rn(wv[j]);
      lo[j] = f2bf_rn(wv[j] - bf2f(hi[j]));
    }
    const size_t base = (((size_t)ob_out * 8 + ks) * 64 + l) * 16;
    const size_t sstr = (size_t)nob * 8 * 64 * 16;
    *reinterpret_cast<uint4*>(outb + base) = *reinterpret_cast<const uint4*>(hi);
    *reinterpret_cast<uint4*>(outb + sstr + base) = *reinterpret_cast<const uint4*>(lo);
  }
}

// ---------------------------------------------------------------------------
// K4: fused q/k/v conv (MFMA, 2-split bf16) + BN + LIF. Barrier-free main
// loop: W fragments in LDS (staged once), B spike fragments streamed
// global->VGPR with reg double-buffer (t+1 loads issued before t's MFMAs).
// XCD-bijective swizzle groups the 12 oc-blocks of one (b,ntile) per XCD.
// ---------------------------------------------------------------------------
__global__ __launch_bounds__(256) void k_qkv_mfma(
    const uchar* __restrict__ xsF, const uchar* __restrict__ wfq,
    const float* __restrict__ qga, const float* __restrict__ qbe, const float* __restrict__ qme, const float* __restrict__ qva,
    const float* __restrict__ kga, const float* __restrict__ kbe, const float* __restrict__ kme, const float* __restrict__ kva,
    const float* __restrict__ vga, const float* __restrict__ vbe, const float* __restrict__ vme, const float* __restrict__ vva,
    ushort* __restrict__ qp, uint* __restrict__ flags) {
  __shared__ short wlds[64][64][8];  // [cg=s*32+obl*8+ks][lane][8] = 64 KB
  const int tid = threadIdx.x;
  const int w = tid >> 6, lane = tid & 63;
  const int lhi = lane >> 4, llo = lane & 15;
  const int wr = w >> 1, wc = w & 1;
  // swizzled decode: all 12 oc-blocks of group g=(b,ntile) share one XCD
  const int bid = blockIdx.x;
  const int xcd = bid & 7;
  const int r = bid >> 3;
  const int j = r % 12;                 // oc-block 0..11
  const int g = (r / 12) * 8 + xcd;     // group 0..127
  const int b = g >> 2, ntile = g & 3;
  const int oc0 = j * 64;
  const int sel = j >> 2;
  const float* G  = sel == 0 ? qga : (sel == 1 ? kga : vga);
  const float* Be = sel == 0 ? qbe : (sel == 1 ? kbe : vbe);
  const float* Mn = sel == 0 ? qme : (sel == 1 ? kme : vme);
  const float* Vr = sel == 0 ? qva : (sel == 1 ? kva : vva);

  // stage W fragments (both splits, 4 obs) to LDS: 64 chunk-groups x 1 KB
#pragma unroll
  for (int i = 0; i < 16; ++i) {
    const int cg = w * 16 + i;                 // wave-uniform
    const int s = cg >> 5, rem = cg & 31, obl = rem >> 3, ks = rem & 7;
    const size_t gsrc = ((((size_t)s * 48 + j * 4 + obl) * 8 + ks) * 64 + lane) * 16;
    gload_lds16(wfq + gsrc, reinterpret_cast<char*>(&wlds[0][0][0]) + cg * 1024);
  }

  float inv8[2][4], mean8[2][4], beta8[2][4];
#pragma unroll
  for (int mf = 0; mf < 2; ++mf)
#pragma unroll
    for (int rr = 0; rr < 4; ++rr) {
      const int ocb = (oc0 & 255) + wr * 32 + mf * 16 + lhi * 4 + rr;
      inv8[mf][rr] = G[ocb] / sqrtf(Vr[ocb] + EPSf);
      mean8[mf][rr] = Mn[ocb];
      beta8[mf][rr] = Be[ocb];
    }

  float vst[2][2][4];
#pragma unroll
  for (int mf = 0; mf < 2; ++mf)
#pragma unroll
    for (int nf = 0; nf < 2; ++nf)
#pragma unroll
      for (int rr = 0; rr < 4; ++rr) vst[mf][nf][rr] = 0.f;
  uint fl = 0;
  ushort qm[TT][4];

  const int nb0 = ntile * 4 + wc * 2;
  __syncthreads();  // the ONLY barrier: W-LDS ready

#define BPTR(t_, nb_, ks_)                                              \
  reinterpret_cast<const s16x8*>(                                       \
      xsF + ((((size_t)((t_) * BB + b) * 16 + (nb_)) * 512 + (ks_) * 64 + lane) * 16))

  s16x8 bA[2][8], bB[2][8];
#pragma unroll
  for (int ks = 0; ks < 8; ++ks) {
    bA[0][ks] = *BPTR(0, nb0, ks);
    bA[1][ks] = *BPTR(0, nb0 + 1, ks);
  }

#define QKV_STEP(t_, CUR, NXT, PRE)                                             \
  {                                                                             \
    if (PRE) {                                                                  \
      _Pragma("unroll") for (int ks = 0; ks < 8; ++ks) {                        \
        NXT[0][ks] = *BPTR((t_) + 1, nb0, ks);                                  \
        NXT[1][ks] = *BPTR((t_) + 1, nb0 + 1, ks);                              \
      }                                                                         \
    }                                                                           \
    f32x4 acc[2][2];                                                            \
    _Pragma("unroll") for (int mf = 0; mf < 2; ++mf)                            \
        _Pragma("unroll") for (int nf = 0; nf < 2; ++nf)                        \
            acc[mf][nf] = (f32x4){0.f, 0.f, 0.f, 0.f};                          \
    _Pragma("unroll") for (int ks = 0; ks < 8; ++ks) {                          \
      _Pragma("unroll") for (int s = 0; s < 2; ++s)                             \
          _Pragma("unroll") for (int mf = 0; mf < 2; ++mf) {                    \
        s16x8 wf = *reinterpret_cast<const s16x8*>(                             \
            &wlds[s * 32 + (wr * 2 + mf) * 8 + ks][lane][0]);                   \
        acc[mf][0] = __builtin_amdgcn_mfma_f32_16x16x32_bf16(wf, CUR[0][ks],    \
                                                             acc[mf][0], 0, 0, 0); \
        acc[mf][1] = __builtin_amdgcn_mfma_f32_16x16x32_bf16(wf, CUR[1][ks],    \
                                                             acc[mf][1], 0, 0, 0); \
      }                                                                         \
    }                                                                           \
    _Pragma("unroll") for (int mf = 0; mf < 2; ++mf)                            \
        _Pragma("unroll") for (int nf = 0; nf < 2; ++nf)                        \
            _Pragma("unroll") for (int rr = 0; rr < 4; ++rr) {                  \
      float y = (acc[mf][nf][rr] - mean8[mf][rr]) * inv8[mf][rr] + beta8[mf][rr]; \
      float v = vst[mf][nf][rr];                                                \
      v = v + (y - v) * 0.5f;                                                   \
      const bool sp = (v >= 1.0f);                                              \
      if (fabsf(v - 1.0f) < MARGINf) fl |= 1u << ((mf * 2 + nf) * 4 + rr);      \
      const unsigned long long m = __ballot(sp);                                \
      if (llo == rr) qm[t_][mf * 2 + nf] = (ushort)((m >> (lhi * 16)) & 0xFFFFull); \
      vst[mf][nf][rr] = sp ? 0.f : v;                                           \
    }                                                                           \
  }

  QKV_STEP(0, bA, bB, 1)
  QKV_STEP(1, bB, bA, 1)
  QKV_STEP(2, bA, bB, 1)
  QKV_STEP(3, bB, bA, 0)
#undef QKV_STEP
#undef BPTR

  // deferred packed-spike writes
  if (llo < 4) {
#pragma unroll
    for (int t = 0; t < TT; ++t) {
      ushort* qrow = qp + (size_t)(t * BB + b) * 768 * 16;
#pragma unroll
      for (int mf = 0; mf < 2; ++mf)
#pragma unroll
        for (int nf = 0; nf < 2; ++nf) {
          const int oc = oc0 + wr * 32 + mf * 16 + lhi * 4 + llo;
          qrow[(size_t)oc * 16 + ntile * 4 + wc * 2 + nf] = qm[t][mf * 2 + nf];
        }
    }
  }

  if (fl) {
    const int cnt = __popc(fl);
    uint base = atomicAdd(flags, (uint)cnt);
#pragma unroll
    for (int mf = 0; mf < 2; ++mf)
#pragma unroll
      for (int nf = 0; nf < 2; ++nf)
#pragma unroll
        for (int rr = 0; rr < 4; ++rr)
          if (fl & (1u << ((mf * 2 + nf) * 4 + rr))) {
            const int oc = oc0 + wr * 32 + mf * 16 + lhi * 4 + rr;
            const int n = ntile * 64 + wc * 32 + nf * 16 + llo;
            if (base < FLAG_CAP) flags[4 + base] = (((uint)(b << 10) | (uint)oc) << 8) | (uint)n;
            base++;
          }
  }
}

// ---------------------------------------------------------------------------
// K5: exact fixer on packed spike bits (validated round-3 version).
// ---------------------------------------------------------------------------
__global__ __launch_bounds__(256) void k_fix(
    const uchar* __restrict__ xsP,
    const float* __restrict__ qw, const float* __restrict__ kw, const float* __restrict__ vw,
    const float* __restrict__ qga, const float* __restrict__ qbe, const float* __restrict__ qme, const float* __restrict__ qva,
    const float* __restrict__ kga, const float* __restrict__ kbe, const float* __restrict__ kme, const float* __restrict__ kva,
    const float* __restrict__ vga, const float* __restrict__ vbe, const float* __restrict__ vme, const float* __restrict__ vva,
    uint* __restrict__ qp32, const uint* __restrict__ flags) {
#pragma clang fp contract(off)
  const uint cnt = min(flags[0], FLAG_CAP);
  for (uint i = blockIdx.x * 256 + threadIdx.x; i < cnt; i += gridDim.x * 256) {
    const uint e = flags[4 + i];
    const int n = e & 255;
    const int oc = (e >> 8) & 1023;
    const int b = e >> 18;
    const int sel = oc >> 8, ocl = oc & 255;
    const float* W = (sel == 0 ? qw : (sel == 1 ? kw : vw)) + (size_t)ocl * CC;
    const float* G  = sel == 0 ? qga : (sel == 1 ? kga : vga);
    const float* Be = sel == 0 ? qbe : (sel == 1 ? kbe : vbe);
    const float* Mn = sel == 0 ? qme : (sel == 1 ? kme : vme);
    const float* Vr = sel == 0 ? qva : (sel == 1 ? kva : vva);

    uint bw[4][8];
#pragma unroll
    for (int t = 0; t < TT; ++t) {
      const uint4* p = reinterpret_cast<const uint4*>(
          xsP + (((size_t)(t * BB + b) * NN + n) << 5));
      uint4 a = p[0], c4 = p[1];
      bw[t][0] = a.x;  bw[t][1] = a.y;  bw[t][2] = a.z;  bw[t][3] = a.w;
      bw[t][4] = c4.x; bw[t][5] = c4.y; bw[t][6] = c4.z; bw[t][7] = c4.w;
    }

    const float4* W4 = reinterpret_cast<const float4*>(W);
    float a0 = 0.f, a1 = 0.f, a2 = 0.f, a3 = 0.f;
#pragma unroll
    for (int g = 0; g < 32; ++g) {
      const float4 w0 = W4[2 * g];
      const float4 w1 = W4[2 * g + 1];
      const uint s0 = bw[0][g >> 2] >> ((g & 3) * 8);
      const uint s1 = bw[1][g >> 2] >> ((g & 3) * 8);
      const uint s2 = bw[2][g >> 2] >> ((g & 3) * 8);
      const uint s3 = bw[3][g >> 2] >> ((g & 3) * 8);
      const float wv[8] = {w0.x, w0.y, w0.z, w0.w, w1.x, w1.y, w1.z, w1.w};
#pragma unroll
      for (int jj = 0; jj < 8; ++jj) {
        a0 = fmaf(wv[jj], (float)((s0 >> jj) & 1u), a0);
        a1 = fmaf(wv[jj], (float)((s1 >> jj) & 1u), a1);
        a2 = fmaf(wv[jj], (float)((s2 >> jj) & 1u), a2);
        a3 = fmaf(wv[jj], (float)((s3 >> jj) & 1u), a3);
      }
    }
    float accs[4] = {a0, a1, a2, a3};

    const float inv = G[ocl] / sqrtf(Vr[ocl] + EPSf);
    const float mean = Mn[ocl], beta = Be[ocl];
    float v = 0.f;
#pragma unroll
    for (int t = 0; t < TT; ++t) {
      float xm = accs[t] - mean;
      float y = xm * inv;
      y = y + beta;
      float d = (y - v) * 0.5f;
      v = v + d;
      const bool sp = (v >= 1.0f);
      const size_t widx = ((size_t)(t * BB + b) * 768 + oc) * 8 + (n >> 5);
      const uint bit = 1u << (n & 31);
      if (sp) atomicOr(&qp32[widx], bit);
      else atomicAnd(&qp32[widx], ~bit);
      if (sp) v = 0.f;
    }
  }
}

// ---------------------------------------------------------------------------
// K6: attention Q(K^T V)*2scale + LIF, exact integers, 1024-thread blocks.
// ---------------------------------------------------------------------------
__global__ __launch_bounds__(1024) void k_attn(const ushort* __restrict__ qp,
                                               uchar* __restrict__ attnF) {
  __shared__ uint Qb[32][8], Kb[32][8], Vb[32][8];
  __shared__ int KtV[32][32];
  const int tid = threadIdx.x;
  const int b = blockIdx.x >> 3;
  const int h = blockIdx.x & 7;
  const int n = tid & 255;
  const int jg = tid >> 8;  // 0..3, wave-uniform
  const int wordn = n >> 5, bitn = n & 31;

  float vst[8];
#pragma unroll
  for (int j = 0; j < 8; ++j) vst[j] = 0.f;

  for (int t = 0; t < TT; ++t) {
    __syncthreads();
    const ushort* base = qp + (size_t)(t * BB + b) * 768 * 16;
    if (tid < 768) {
      const int arr = tid >> 8;  // 0=Q 1=K 2=V
      const int idx = tid & 255;
      const int ch = idx >> 3, wv2 = idx & 7;
      const uint val = *reinterpret_cast<const uint*>(
          base + (size_t)(arr * 256 + h * 32 + ch) * 16 + wv2 * 2);
      uint(*dst)[8] = (arr == 0) ? Qb : (arr == 1) ? Kb : Vb;
      dst[ch][wv2] = val;
    }
    __syncthreads();
    {
      const int ii = tid >> 5, jj = tid & 31;
      int s = 0;
#pragma unroll
      for (int w8 = 0; w8 < 8; ++w8) s += __popc(Kb[ii][w8] & Vb[jj][w8]);
      KtV[ii][jj] = s;
    }
    __syncthreads();
    int acc[8];
#pragma unroll
    for (int j = 0; j < 8; ++j) acc[j] = 0;
#pragma unroll 4
    for (int ii = 0; ii < 32; ++ii) {
      const int qb = (int)((Qb[ii][wordn] >> bitn) & 1u);
      const int4 k0 = *reinterpret_cast<const int4*>(&KtV[ii][jg * 8]);
      const int4 k1 = *reinterpret_cast<const int4*>(&KtV[ii][jg * 8 + 4]);
      acc[0] += k0.x * qb; acc[1] += k0.y * qb;
      acc[2] += k0.z * qb; acc[3] += k0.w * qb;
      acc[4] += k1.x * qb; acc[5] += k1.y * qb;
      acc[6] += k1.z * qb; acc[7] += k1.w * qb;
    }
    ushort sbit[8];
    {
#pragma clang fp contract(off)
#pragma unroll
      for (int j = 0; j < 8; ++j) {
        float y = (float)acc[j] * MULTf;
        float v = vst[j];
        float d = (y - v) * 0.5f;
        v = v + d;
        const bool sp = (v >= 1.0f);
        sbit[j] = sp ? (ushort)0x3F80 : (ushort)0;
        vst[j] = sp ? 0.f : v;
      }
    }
    uint4 o;
    o.x = (uint)sbit[0] | ((uint)sbit[1] << 16);
    o.y = (uint)sbit[2] | ((uint)sbit[3] << 16);
    o.z = (uint)sbit[4] | ((uint)sbit[5] << 16);
    o.w = (uint)sbit[6] | ((uint)sbit[7] << 16);
    uint4* dst4 = reinterpret_cast<uint4*>(attnF) +
                  (((size_t)(t * BB + b) * 16 + (n >> 4)) * 512 + h * 64 + jg * 16 + (n & 15));
    *dst4 = o;
  }
}

// ---------------------------------------------------------------------------
// K7: proj conv (MFMA, 2-split) + BN -> f32 out. No LDS, no barriers:
// W frags in regs, B frags direct global->reg. XCD-bijective swizzle.
// ---------------------------------------------------------------------------
__global__ __launch_bounds__(256) void k_proj_mfma(
    const uchar* __restrict__ attnF, const uchar* __restrict__ wfp,
    const float* __restrict__ pga, const float* __restrict__ pbe,
    const float* __restrict__ pme, const float* __restrict__ pva,
    float* __restrict__ out) {
  const int tid = threadIdx.x;
  const int w = tid >> 6, lane = tid & 63;
  const int lhi = lane >> 4, llo = lane & 15;
  const int wr = w >> 1, wc = w & 1;
  const int bid = blockIdx.x;
  const int xcd = bid & 7;
  const int r = bid >> 3;
  const int j = r & 3;                // oc-block 0..3
  const int g = (r >> 2) * 8 + xcd;   // group 0..511 = (tb, ntile)
  const int tb = g >> 2, ntile = g & 3;
  const int oc0 = j * 64;

  s16x8 wfr[2][2][8];
#pragma unroll
  for (int s = 0; s < 2; ++s)
#pragma unroll
    for (int mf = 0; mf < 2; ++mf) {
      const int ob = j * 4 + wr * 2 + mf;
#pragma unroll
      for (int ks = 0; ks < 8; ++ks)
        wfr[s][mf][ks] = *reinterpret_cast<const s16x8*>(
            wfp + ((((size_t)s * 16 + ob) * 8 + ks) * 64 + lane) * 16);
    }

  // B fragments direct from global (same bits LDS held before)
  const int nb0 = ntile * 4 + wc * 2;
  s16x8 bfr[2][8];
#pragma unroll
  for (int ks = 0; ks < 8; ++ks) {
    bfr[0][ks] = *reinterpret_cast<const s16x8*>(
        attnF + ((((size_t)tb * 16 + nb0) * 512 + ks * 64 + lane) * 16));
    bfr[1][ks] = *reinterpret_cast<const s16x8*>(
        attnF + ((((size_t)tb * 16 + nb0 + 1) * 512 + ks * 64 + lane) * 16));
  }

  float inv8[2][4], mean8[2][4], beta8[2][4];
#pragma unroll
  for (int mf = 0; mf < 2; ++mf)
#pragma unroll
    for (int rr = 0; rr < 4; ++rr) {
      const int ocb = oc0 + wr * 32 + mf * 16 + lhi * 4 + rr;
      inv8[mf][rr] = pga[ocb] / sqrtf(pva[ocb] + EPSf);
      mean8[mf][rr] = pme[ocb];
      beta8[mf][rr] = pbe[ocb];
    }

  f32x4 acc[2][2];
#pragma unroll
  for (int mf = 0; mf < 2; ++mf)
#pragma unroll
    for (int nf = 0; nf < 2; ++nf) acc[mf][nf] = (f32x4){0.f, 0.f, 0.f, 0.f};

#pragma unroll
  for (int ks = 0; ks < 8; ++ks) {
#pragma unroll
    for (int s = 0; s < 2; ++s)
#pragma unroll
      for (int mf = 0; mf < 2; ++mf) {
        acc[mf][0] = __builtin_amdgcn_mfma_f32_16x16x32_bf16(wfr[s][mf][ks], bfr[0][ks], acc[mf][0], 0, 0, 0);
        acc[mf][1] = __builtin_amdgcn_mfma_f32_16x16x32_bf16(wfr[s][mf][ks], bfr[1][ks], acc[mf][1], 0, 0, 0);
      }
  }

#pragma unroll
  for (int mf = 0; mf < 2; ++mf)
#pragma unroll
    for (int nf = 0; nf < 2; ++nf)
#pragma unroll
      for (int rr = 0; rr < 4; ++rr) {
        const int oc = oc0 + wr * 32 + mf * 16 + lhi * 4 + rr;
        const int nn = ntile * 64 + wc * 32 + nf * 16 + llo;
        float y = (acc[mf][nf][rr] - mean8[mf][rr]) * inv8[mf][rr] + beta8[mf][rr];
        out[((size_t)tb * CC + oc) * NN + nn] = y;
      }
}

// ---------------------------------------------------------------------------
extern "C" void kernel_launch(void* const* d_in, const int* in_sizes, int n_in,
                              void* d_out, int out_size, void* d_ws, size_t ws_size,
                              hipStream_t stream) {
  const float* x = (const float*)d_in[0];
  const float* q_w = (const float*)d_in[1];
  const float* q_g = (const float*)d_in[2];
  const float* q_b = (const float*)d_in[3];
  const float* q_m = (const float*)d_in[4];
  const float* q_v = (const float*)d_in[5];
  const float* k_w = (const float*)d_in[6];
  const float* k_g = (const float*)d_in[7];
  const float* k_b = (const float*)d_in[8];
  const float* k_m = (const float*)d_in[9];
  const float* k_v = (const float*)d_in[10];
  const float* v_w = (const float*)d_in[11];
  const float* v_g = (const float*)d_in[12];
  const float* v_b = (const float*)d_in[13];
  const float* v_m = (const float*)d_in[14];
  const float* v_v = (const float*)d_in[15];
  const float* p_w = (const float*)d_in[16];
  const float* p_g = (const float*)d_in[17];
  const float* p_b = (const float*)d_in[18];
  const float* p_m = (const float*)d_in[19];
  const float* p_v = (const float*)d_in[20];

  uchar* ws = (uchar*)d_ws;
  uchar* xsF  = ws;                         // 16 MiB frags (reused as attnF)
  ushort* qp  = (ushort*)(ws + 16777216);   // 3 MiB packed q/k/v spikes
  uchar* wfq  = ws + 19922944;              // 768 KiB
  uchar* wfp  = ws + 20709376;              // 256 KiB
  uint* flags = (uint*)(ws + 20971520);     // 16 B counter + list (2 MiB)
  uchar* xsP  = ws + 23068672;              // 1 MiB bit-packed xs spikes

  k_front<<<dim3(1152), 256, 0, stream>>>(x, xsF, xsP, q_w, k_w, v_w, p_w,
                                          wfq, wfp, flags);
  k_qkv_mfma<<<dim3(1536), 256, 0, stream>>>(xsF, wfq,
                                             q_g, q_b, q_m, q_v,
                                             k_g, k_b, k_m, k_v,
                                             v_g, v_b, v_m, v_v,
                                             qp, flags);
  k_fix<<<dim3(64), 256, 0, stream>>>(xsP, q_w, k_w, v_w,
                                      q_g, q_b, q_m, q_v,
                                      k_g, k_b, k_m, k_v,
                                      v_g, v_b, v_m, v_v,
                                      (uint*)qp, flags);
  k_attn<<<dim3(256), 1024, 0, stream>>>(qp, xsF /* attnF shares region */);
  k_proj_mfma<<<dim3(2048), 256, 0, stream>>>(xsF, wfp, p_g, p_b, p_m, p_v,
                                              (float*)d_out);
}

// Round 7
// 111.010 us; speedup vs baseline: 1.0280x; 1.0120x over previous
//
#include <hip/hip_runtime.h>

#define TT 4
#define BB 32
#define CC 256
#define NN 256
#define EPSf 1e-5f
#define MULTf 0.35355339059327373f
#define MARGINQ 1e-2f
#define FLAG_CAP 2097152u

typedef __attribute__((ext_vector_type(8))) short s16x8;
typedef __attribute__((ext_vector_type(4))) float f32x4;
typedef unsigned char uchar;
typedef unsigned int uint;
typedef unsigned short ushort;

// bf16 round-to-nearest-even
__device__ __forceinline__ ushort f2bf_rn(float f) {
  uint u = __float_as_uint(f);
  u = (u + 0x7FFFu + ((u >> 16) & 1u)) >> 16;
  return (ushort)u;
}
__device__ __forceinline__ float bf2f(ushort b) {
  return __uint_as_float(((uint)b) << 16);
}

// ---------------------------------------------------------------------------
// K1 (merged front): blocks 0..255 = lif(x) -> xsF fragments + xsP packed
// bits (float4 x loads, thread = 8c x 4n). Blocks 256..383 = weight prep:
// qkv single-split bf16 scaled by BN inv; proj 2-way split. Zeroes flags.
// LIF bitwise-exact (halving exact, contract off).
// ---------------------------------------------------------------------------
__global__ __launch_bounds__(256) void k_front(
    const float* __restrict__ x, uchar* __restrict__ xsF, uchar* __restrict__ xsP,
    const float* __restrict__ qw, const float* __restrict__ kw,
    const float* __restrict__ vw, const float* __restrict__ pw,
    const float* __restrict__ qga, const float* __restrict__ qva,
    const float* __restrict__ kga, const float* __restrict__ kva,
    const float* __restrict__ vga, const float* __restrict__ vva,
    uchar* __restrict__ wfq, uchar* __restrict__ wfp, uint* __restrict__ flags) {
  const int tid = threadIdx.x;
  const int bid = blockIdx.x;
  if (bid < 256) {
#pragma clang fp contract(off)
    const int b = bid >> 3;
    const int ksq = bid & 7;
    const int oct = tid >> 6;    // 0..3
    const int nq = tid & 63;     // n-quad
    const int c0 = ksq * 32 + oct * 8;
    const int n0 = nq * 4;
    const size_t stride = (size_t)BB * CC * NN;
    const float* xb = x + ((size_t)b * CC + c0) * NN + n0;

    float v[8][4];
#pragma unroll
    for (int j = 0; j < 8; ++j)
#pragma unroll
      for (int nn = 0; nn < 4; ++nn) v[j][nn] = 0.f;

#pragma unroll
    for (int t = 0; t < TT; ++t) {
      ushort sp[8][4];
      uint pm[4] = {0, 0, 0, 0};
#pragma unroll
      for (int j = 0; j < 8; ++j) {
        const float4 xv = *reinterpret_cast<const float4*>(xb + t * stride + (size_t)j * NN);
        const float xa[4] = {xv.x, xv.y, xv.z, xv.w};
#pragma unroll
        for (int nn = 0; nn < 4; ++nn) {
          float d = (xa[nn] - v[j][nn]) * 0.5f;
          v[j][nn] = v[j][nn] + d;
          bool s = (v[j][nn] >= 1.0f);
          sp[j][nn] = s ? (ushort)0x3F80 : (ushort)0;
          if (s) { v[j][nn] = 0.f; pm[nn] |= 1u << j; }
        }
      }
#pragma unroll
      for (int nn = 0; nn < 4; ++nn) {
        const int n = n0 + nn;
        uint4* dst = reinterpret_cast<uint4*>(xsF) +
                     (((size_t)(t * BB + b) * 16 + (n >> 4)) * 512 + ksq * 64 + oct * 16 + (n & 15));
        uint4 o;
        o.x = (uint)sp[0][nn] | ((uint)sp[1][nn] << 16);
        o.y = (uint)sp[2][nn] | ((uint)sp[3][nn] << 16);
        o.z = (uint)sp[4][nn] | ((uint)sp[5][nn] << 16);
        o.w = (uint)sp[6][nn] | ((uint)sp[7][nn] << 16);
        *dst = o;
        xsP[(((size_t)(t * BB + b) * NN + n) << 5) + ksq * 4 + oct] = (uchar)pm[nn];
      }
    }
  } else {
    const int gid = (bid - 256) * 256 + tid;  // 0..32767
    if (gid < 4) flags[gid] = 0;
    const int ob2 = gid >> 9;                 // 0..63
    const int e = gid & 511;
    const int ks = e >> 6, l = e & 63;
    const int c0 = ks * 32 + (l >> 4) * 8;
    if (ob2 < 48) {
      // qkv: single split, scaled by BN inv
      const int sel = ob2 >> 4;
      const float* Wb = sel == 0 ? qw : (sel == 1 ? kw : vw);
      const float* G = sel == 0 ? qga : (sel == 1 ? kga : vga);
      const float* Vr = sel == 0 ? qva : (sel == 1 ? kva : vva);
      const int ocr = (ob2 & 15) * 16 + (l & 15);
      const float inv = G[ocr] / sqrtf(Vr[ocr] + EPSf);
      const float* W = Wb + (size_t)ocr * CC;
      float wv[8];
      *reinterpret_cast<float4*>(&wv[0]) = *reinterpret_cast<const float4*>(W + c0);
      *reinterpret_cast<float4*>(&wv[4]) = *reinterpret_cast<const float4*>(W + c0 + 4);
      ushort hi[8];
#pragma unroll
      for (int j = 0; j < 8; ++j) hi[j] = f2bf_rn(wv[j] * inv);
      *reinterpret_cast<uint4*>(wfq + (((size_t)ob2 * 8 + ks) * 64 + l) * 16) =
          *reinterpret_cast<const uint4*>(hi);
    } else {
      // proj: 2-way split, unscaled (validated path)
      const int ob = ob2 - 48;
      const float* W = pw + ((size_t)(ob * 16 + (l & 15))) * CC;
      float wv[8];
      *reinterpret_cast<float4*>(&wv[0]) = *reinterpret_cast<const float4*>(W + c0);
      *reinterpret_cast<float4*>(&wv[4]) = *reinterpret_cast<const float4*>(W + c0 + 4);
      ushort hi[8], lo[8];
#pragma unroll
      for (int j = 0; j < 8; ++j) {
        hi[j] = f2bf_rn(wv[j]);
        lo[j] = f2bf_rn(wv[j] - bf2f(hi[j]));
      }
      const size_t base = (((size_t)ob * 8 + ks) * 64 + l) * 16;
      const size_t sstr = (size_t)16 * 8 * 64 * 16;
      *reinterpret_cast<uint4*>(wfp + base) = *reinterpret_cast<const uint4*>(hi);
      *reinterpret_cast<uint4*>(wfp + sstr + base) = *reinterpret_cast<const uint4*>(lo);
    }
  }
}

// ---------------------------------------------------------------------------
// K4: fused q/k/v conv (MFMA, single-split scaled bf16) + folded-BN + LIF.
// No LDS, no barriers. Wave = 64oc x 16n (mf=4): W frags 128 VGPR loaded
// once; B spike chunks global->reg, reload-after-use, one t ahead.
// XCD-bijective swizzle groups the 12 oc-blocks of one (b,ntile) per XCD.
// ---------------------------------------------------------------------------
__global__ __launch_bounds__(256, 2) void k_qkv_mfma(
    const uchar* __restrict__ xsF, const uchar* __restrict__ wfq,
    const float* __restrict__ qga, const float* __restrict__ qbe, const float* __restrict__ qme, const float* __restrict__ qva,
    const float* __restrict__ kga, const float* __restrict__ kbe, const float* __restrict__ kme, const float* __restrict__ kva,
    const float* __restrict__ vga, const float* __restrict__ vbe, const float* __restrict__ vme, const float* __restrict__ vva,
    ushort* __restrict__ qp, uint* __restrict__ flags) {
  const int tid = threadIdx.x;
  const int wc = tid >> 6, lane = tid & 63;
  const int lhi = lane >> 4, llo = lane & 15;
  const int bid = blockIdx.x;
  const int xcd = bid & 7;
  const int r0 = bid >> 3;
  const int j = r0 % 12;                // oc-block 0..11
  const int g = (r0 / 12) * 8 + xcd;    // group 0..127
  const int b = g >> 2, ntile = g & 3;
  const int oc0 = j * 64;
  const int sel = j >> 2;
  const float* G  = sel == 0 ? qga : (sel == 1 ? kga : vga);
  const float* Be = sel == 0 ? qbe : (sel == 1 ? kbe : vbe);
  const float* Mn = sel == 0 ? qme : (sel == 1 ? kme : vme);
  const float* Vr = sel == 0 ? qva : (sel == 1 ? kva : vva);

  // W fragments: 4 mf x 8 ks (single split) = 128 VGPR
  s16x8 wfr[4][8];
#pragma unroll
  for (int mf = 0; mf < 4; ++mf)
#pragma unroll
    for (int ks = 0; ks < 8; ++ks)
      wfr[mf][ks] = *reinterpret_cast<const s16x8*>(
          wfq + (((size_t)(j * 4 + mf) * 8 + ks) * 64 + lane) * 16);

  // folded BN bias: y = acc + bias
  float bias8[4][4];
#pragma unroll
  for (int mf = 0; mf < 4; ++mf)
#pragma unroll
    for (int rr = 0; rr < 4; ++rr) {
      const int ocb = (j & 3) * 64 + mf * 16 + lhi * 4 + rr;
      const float inv = G[ocb] / sqrtf(Vr[ocb] + EPSf);
      bias8[mf][rr] = Be[ocb] - Mn[ocb] * inv;
    }

  float vst[4][4];
#pragma unroll
  for (int mf = 0; mf < 4; ++mf)
#pragma unroll
    for (int rr = 0; rr < 4; ++rr) vst[mf][rr] = 0.f;
  uint fl = 0;
  ushort qm[TT][4];

  const int nb = ntile * 4 + wc;

#define BPTR(t_, ks_)                                                   \
  reinterpret_cast<const s16x8*>(                                       \
      xsF + ((((size_t)((t_) * BB + b) * 16 + nb) * 512 + (ks_) * 64 + lane) * 16))

  s16x8 bfr[8];
#pragma unroll
  for (int ks = 0; ks < 8; ++ks) bfr[ks] = *BPTR(0, ks);

#pragma unroll
  for (int t = 0; t < TT; ++t) {
    f32x4 acc[4];
#pragma unroll
    for (int mf = 0; mf < 4; ++mf) acc[mf] = (f32x4){0.f, 0.f, 0.f, 0.f};

#pragma unroll
    for (int ks = 0; ks < 8; ++ks) {
#pragma unroll
      for (int mf = 0; mf < 4; ++mf)
        acc[mf] = __builtin_amdgcn_mfma_f32_16x16x32_bf16(wfr[mf][ks], bfr[ks], acc[mf], 0, 0, 0);
      if (t < TT - 1) bfr[ks] = *BPTR(t + 1, ks);  // reload for next t
    }

    // folded-BN + LIF epilogue (registers only)
#pragma unroll
    for (int mf = 0; mf < 4; ++mf)
#pragma unroll
      for (int rr = 0; rr < 4; ++rr) {
        float y = acc[mf][rr] + bias8[mf][rr];
        float v = vst[mf][rr];
        v = v + (y - v) * 0.5f;
        const bool sp = (v >= 1.0f);
        if (fabsf(v - 1.0f) < MARGINQ) fl |= 1u << (mf * 4 + rr);
        const unsigned long long m = __ballot(sp);
        if (llo == rr) qm[t][mf] = (ushort)((m >> (lhi * 16)) & 0xFFFFull);
        vst[mf][rr] = sp ? 0.f : v;
      }
  }
#undef BPTR

  // deferred packed-spike writes
  if (llo < 4) {
#pragma unroll
    for (int t = 0; t < TT; ++t) {
      ushort* qrow = qp + (size_t)(t * BB + b) * 768 * 16;
#pragma unroll
      for (int mf = 0; mf < 4; ++mf) {
        const int oc = oc0 + mf * 16 + lhi * 4 + llo;
        qrow[(size_t)oc * 16 + ntile * 4 + wc] = qm[t][mf];
      }
    }
  }

  if (fl) {
    const int cnt = __popc(fl);
    uint base = atomicAdd(flags, (uint)cnt);
#pragma unroll
    for (int mf = 0; mf < 4; ++mf)
#pragma unroll
      for (int rr = 0; rr < 4; ++rr)
        if (fl & (1u << (mf * 4 + rr))) {
          const int oc = oc0 + mf * 16 + lhi * 4 + rr;
          const int n = ntile * 64 + wc * 16 + llo;
          if (base < FLAG_CAP) flags[4 + base] = (((uint)(b << 10) | (uint)oc) << 8) | (uint)n;
          base++;
        }
  }
}

// ---------------------------------------------------------------------------
// K5: exact fixer on packed spike bits (validated). Recomputes flagged
// (b,oc,n) with the bitwise-exact ascending-c f32 chain, patches qp bits.
// ---------------------------------------------------------------------------
__global__ __launch_bounds__(256) void k_fix(
    const uchar* __restrict__ xsP,
    const float* __restrict__ qw, const float* __restrict__ kw, const float* __restrict__ vw,
    const float* __restrict__ qga, const float* __restrict__ qbe, const float* __restrict__ qme, const float* __restrict__ qva,
    const float* __restrict__ kga, const float* __restrict__ kbe, const float* __restrict__ kme, const float* __restrict__ kva,
    const float* __restrict__ vga, const float* __restrict__ vbe, const float* __restrict__ vme, const float* __restrict__ vva,
    uint* __restrict__ qp32, const uint* __restrict__ flags) {
#pragma clang fp contract(off)
  const uint cnt = min(flags[0], FLAG_CAP);
  for (uint i = blockIdx.x * 256 + threadIdx.x; i < cnt; i += gridDim.x * 256) {
    const uint e = flags[4 + i];
    const int n = e & 255;
    const int oc = (e >> 8) & 1023;
    const int b = e >> 18;
    const int sel = oc >> 8, ocl = oc & 255;
    const float* W = (sel == 0 ? qw : (sel == 1 ? kw : vw)) + (size_t)ocl * CC;
    const float* G  = sel == 0 ? qga : (sel == 1 ? kga : vga);
    const float* Be = sel == 0 ? qbe : (sel == 1 ? kbe : vbe);
    const float* Mn = sel == 0 ? qme : (sel == 1 ? kme : vme);
    const float* Vr = sel == 0 ? qva : (sel == 1 ? kva : vva);

    uint bw[4][8];
#pragma unroll
    for (int t = 0; t < TT; ++t) {
      const uint4* p = reinterpret_cast<const uint4*>(
          xsP + (((size_t)(t * BB + b) * NN + n) << 5));
      uint4 a = p[0], c4 = p[1];
      bw[t][0] = a.x;  bw[t][1] = a.y;  bw[t][2] = a.z;  bw[t][3] = a.w;
      bw[t][4] = c4.x; bw[t][5] = c4.y; bw[t][6] = c4.z; bw[t][7] = c4.w;
    }

    const float4* W4 = reinterpret_cast<const float4*>(W);
    float a0 = 0.f, a1 = 0.f, a2 = 0.f, a3 = 0.f;
#pragma unroll
    for (int gg = 0; gg < 32; ++gg) {
      const float4 w0 = W4[2 * gg];
      const float4 w1 = W4[2 * gg + 1];
      const uint s0 = bw[0][gg >> 2] >> ((gg & 3) * 8);
      const uint s1 = bw[1][gg >> 2] >> ((gg & 3) * 8);
      const uint s2 = bw[2][gg >> 2] >> ((gg & 3) * 8);
      const uint s3 = bw[3][gg >> 2] >> ((gg & 3) * 8);
      const float wv[8] = {w0.x, w0.y, w0.z, w0.w, w1.x, w1.y, w1.z, w1.w};
#pragma unroll
      for (int jj = 0; jj < 8; ++jj) {
        a0 = fmaf(wv[jj], (float)((s0 >> jj) & 1u), a0);
        a1 = fmaf(wv[jj], (float)((s1 >> jj) & 1u), a1);
        a2 = fmaf(wv[jj], (float)((s2 >> jj) & 1u), a2);
        a3 = fmaf(wv[jj], (float)((s3 >> jj) & 1u), a3);
      }
    }
    float accs[4] = {a0, a1, a2, a3};

    const float inv = G[ocl] / sqrtf(Vr[ocl] + EPSf);
    const float mean = Mn[ocl], beta = Be[ocl];
    float v = 0.f;
#pragma unroll
    for (int t = 0; t < TT; ++t) {
      float xm = accs[t] - mean;
      float y = xm * inv;
      y = y + beta;
      float d = (y - v) * 0.5f;
      v = v + d;
      const bool sp = (v >= 1.0f);
      const size_t widx = ((size_t)(t * BB + b) * 768 + oc) * 8 + (n >> 5);
      const uint bit = 1u << (n & 31);
      if (sp) atomicOr(&qp32[widx], bit);
      else atomicAnd(&qp32[widx], ~bit);
      if (sp) v = 0.f;
    }
  }
}

// ---------------------------------------------------------------------------
// K6: attention Q(K^T V)*2scale + LIF, exact integers, 1024-thread blocks.
// ---------------------------------------------------------------------------
__global__ __launch_bounds__(1024) void k_attn(const ushort* __restrict__ qp,
                                               uchar* __restrict__ attnF) {
  __shared__ uint Qb[32][8], Kb[32][8], Vb[32][8];
  __shared__ int KtV[32][32];
  const int tid = threadIdx.x;
  const int b = blockIdx.x >> 3;
  const int h = blockIdx.x & 7;
  const int n = tid & 255;
  const int jg = tid >> 8;  // 0..3, wave-uniform
  const int wordn = n >> 5, bitn = n & 31;

  float vst[8];
#pragma unroll
  for (int j = 0; j < 8; ++j) vst[j] = 0.f;

  for (int t = 0; t < TT; ++t) {
    __syncthreads();
    const ushort* base = qp + (size_t)(t * BB + b) * 768 * 16;
    if (tid < 768) {
      const int arr = tid >> 8;  // 0=Q 1=K 2=V
      const int idx = tid & 255;
      const int ch = idx >> 3, wv2 = idx & 7;
      const uint val = *reinterpret_cast<const uint*>(
          base + (size_t)(arr * 256 + h * 32 + ch) * 16 + wv2 * 2);
      uint(*dst)[8] = (arr == 0) ? Qb : (arr == 1) ? Kb : Vb;
      dst[ch][wv2] = val;
    }
    __syncthreads();
    {
      const int ii = tid >> 5, jj = tid & 31;
      int s = 0;
#pragma unroll
      for (int w8 = 0; w8 < 8; ++w8) s += __popc(Kb[ii][w8] & Vb[jj][w8]);
      KtV[ii][jj] = s;
    }
    __syncthreads();
    int acc[8];
#pragma unroll
    for (int j = 0; j < 8; ++j) acc[j] = 0;
#pragma unroll 4
    for (int ii = 0; ii < 32; ++ii) {
      const int qb = (int)((Qb[ii][wordn] >> bitn) & 1u);
      const int4 k0 = *reinterpret_cast<const int4*>(&KtV[ii][jg * 8]);
      const int4 k1 = *reinterpret_cast<const int4*>(&KtV[ii][jg * 8 + 4]);
      acc[0] += k0.x * qb; acc[1] += k0.y * qb;
      acc[2] += k0.z * qb; acc[3] += k0.w * qb;
      acc[4] += k1.x * qb; acc[5] += k1.y * qb;
      acc[6] += k1.z * qb; acc[7] += k1.w * qb;
    }
    ushort sbit[8];
    {
#pragma clang fp contract(off)
#pragma unroll
      for (int j = 0; j < 8; ++j) {
        float y = (float)acc[j] * MULTf;
        float v = vst[j];
        float d = (y - v) * 0.5f;
        v = v + d;
        const bool sp = (v >= 1.0f);
        sbit[j] = sp ? (ushort)0x3F80 : (ushort)0;
        vst[j] = sp ? 0.f : v;
      }
    }
    uint4 o;
    o.x = (uint)sbit[0] | ((uint)sbit[1] << 16);
    o.y = (uint)sbit[2] | ((uint)sbit[3] << 16);
    o.z = (uint)sbit[4] | ((uint)sbit[5] << 16);
    o.w = (uint)sbit[6] | ((uint)sbit[7] << 16);
    uint4* dst4 = reinterpret_cast<uint4*>(attnF) +
                  (((size_t)(t * BB + b) * 16 + (n >> 4)) * 512 + h * 64 + jg * 16 + (n & 15));
    *dst4 = o;
  }
}

// ---------------------------------------------------------------------------
// K7: proj conv (MFMA, 2-split) + BN -> f32 out. No LDS, no barriers:
// W frags in regs, B frags direct global->reg. XCD-bijective swizzle.
// ---------------------------------------------------------------------------
__global__ __launch_bounds__(256) void k_proj_mfma(
    const uchar* __restrict__ attnF, const uchar* __restrict__ wfp,
    const float* __restrict__ pga, const float* __restrict__ pbe,
    const float* __restrict__ pme, const float* __restrict__ pva,
    float* __restrict__ out) {
  const int tid = threadIdx.x;
  const int w = tid >> 6, lane = tid & 63;
  const int lhi = lane >> 4, llo = lane & 15;
  const int wr = w >> 1, wc = w & 1;
  const int bid = blockIdx.x;
  const int xcd = bid & 7;
  const int r = bid >> 3;
  const int j = r & 3;                // oc-block 0..3
  const int g = (r >> 2) * 8 + xcd;   // group 0..511 = (tb, ntile)
  const int tb = g >> 2, ntile = g & 3;
  const int oc0 = j * 64;

  s16x8 wfr[2][2][8];
#pragma unroll
  for (int s = 0; s < 2; ++s)
#pragma unroll
    for (int mf = 0; mf < 2; ++mf) {
      const int ob = j * 4 + wr * 2 + mf;
#pragma unroll
      for (int ks = 0; ks < 8; ++ks)
        wfr[s][mf][ks] = *reinterpret_cast<const s16x8*>(
            wfp + ((((size_t)s * 16 + ob) * 8 + ks) * 64 + lane) * 16);
    }

  const int nb0 = ntile * 4 + wc * 2;
  s16x8 bfr[2][8];
#pragma unroll
  for (int ks = 0; ks < 8; ++ks) {
    bfr[0][ks] = *reinterpret_cast<const s16x8*>(
        attnF + ((((size_t)tb * 16 + nb0) * 512 + ks * 64 + lane) * 16));
    bfr[1][ks] = *reinterpret_cast<const s16x8*>(
        attnF + ((((size_t)tb * 16 + nb0 + 1) * 512 + ks * 64 + lane) * 16));
  }

  float inv8[2][4], mean8[2][4], beta8[2][4];
#pragma unroll
  for (int mf = 0; mf < 2; ++mf)
#pragma unroll
    for (int rr = 0; rr < 4; ++rr) {
      const int ocb = oc0 + wr * 32 + mf * 16 + lhi * 4 + rr;
      inv8[mf][rr] = pga[ocb] / sqrtf(pva[ocb] + EPSf);
      mean8[mf][rr] = pme[ocb];
      beta8[mf][rr] = pbe[ocb];
    }

  f32x4 acc[2][2];
#pragma unroll
  for (int mf = 0; mf < 2; ++mf)
#pragma unroll
    for (int nf = 0; nf < 2; ++nf) acc[mf][nf] = (f32x4){0.f, 0.f, 0.f, 0.f};

#pragma unroll
  for (int ks = 0; ks < 8; ++ks) {
#pragma unroll
    for (int s = 0; s < 2; ++s)
#pragma unroll
      for (int mf = 0; mf < 2; ++mf) {
        acc[mf][0] = __builtin_amdgcn_mfma_f32_16x16x32_bf16(wfr[s][mf][ks], bfr[0][ks], acc[mf][0], 0, 0, 0);
        acc[mf][1] = __builtin_amdgcn_mfma_f32_16x16x32_bf16(wfr[s][mf][ks], bfr[1][ks], acc[mf][1], 0, 0, 0);
      }
  }

#pragma unroll
  for (int mf = 0; mf < 2; ++mf)
#pragma unroll
    for (int nf = 0; nf < 2; ++nf)
#pragma unroll
      for (int rr = 0; rr < 4; ++rr) {
        const int oc = oc0 + wr * 32 + mf * 16 + lhi * 4 + rr;
        const int nn = ntile * 64 + wc * 32 + nf * 16 + llo;
        float y = (acc[mf][nf][rr] - mean8[mf][rr]) * inv8[mf][rr] + beta8[mf][rr];
        out[((size_t)tb * CC + oc) * NN + nn] = y;
      }
}

// ---------------------------------------------------------------------------
extern "C" void kernel_launch(void* const* d_in, const int* in_sizes, int n_in,
                              void* d_out, int out_size, void* d_ws, size_t ws_size,
                              hipStream_t stream) {
  const float* x = (const float*)d_in[0];
  const float* q_w = (const float*)d_in[1];
  const float* q_g = (const float*)d_in[2];
  const float* q_b = (const float*)d_in[3];
  const float* q_m = (const float*)d_in[4];
  const float* q_v = (const float*)d_in[5];
  const float* k_w = (const float*)d_in[6];
  const float* k_g = (const float*)d_in[7];
  const float* k_b = (const float*)d_in[8];
  const float* k_m = (const float*)d_in[9];
  const float* k_v = (const float*)d_in[10];
  const float* v_w = (const float*)d_in[11];
  const float* v_g = (const float*)d_in[12];
  const float* v_b = (const float*)d_in[13];
  const float* v_m = (const float*)d_in[14];
  const float* v_v = (const float*)d_in[15];
  const float* p_w = (const float*)d_in[16];
  const float* p_g = (const float*)d_in[17];
  const float* p_b = (const float*)d_in[18];
  const float* p_m = (const float*)d_in[19];
  const float* p_v = (const float*)d_in[20];

  uchar* ws = (uchar*)d_ws;
  uchar* xsF  = ws;                         // 16 MiB frags (reused as attnF)
  ushort* qp  = (ushort*)(ws + 16777216);   // 3 MiB packed q/k/v spikes
  uchar* wfq  = ws + 19922944;              // 384 KiB single-split scaled
  uchar* wfp  = ws + 20447232;              // 256 KiB proj 2-split
  uchar* xsP  = ws + 20971520;              // 1 MiB bit-packed xs spikes
  uint* flags = (uint*)(ws + 22020096);     // 16 B counter + 8 MiB list

  k_front<<<dim3(384), 256, 0, stream>>>(x, xsF, xsP, q_w, k_w, v_w, p_w,
                                         q_g, q_v, k_g, k_v, v_g, v_v,
                                         wfq, wfp, flags);
  k_qkv_mfma<<<dim3(1536), 256, 0, stream>>>(xsF, wfq,
                                             q_g, q_b, q_m, q_v,
                                             k_g, k_b, k_m, k_v,
                                             v_g, v_b, v_m, v_v,
                                             qp, flags);
  k_fix<<<dim3(768), 256, 0, stream>>>(xsP, q_w, k_w, v_w,
                                       q_g, q_b, q_m, q_v,
                                       k_g, k_b, k_m, k_v,
                                       v_g, v_b, v_m, v_v,
                                       (uint*)qp, flags);
  k_attn<<<dim3(256), 1024, 0, stream>>>(qp, xsF /* attnF shares region */);
  k_proj_mfma<<<dim3(2048), 256, 0, stream>>>(xsF, wfp, p_g, p_b, p_m, p_v,
                                              (float*)d_out);
}